// Round 3
// baseline (589.550 us; speedup 1.0000x reference)
//
#include <hip/hip_runtime.h>
#include <math.h>
#include <type_traits>

#define IMG_H 512
#define IMG_W 512
#define NIMG 64
#define TH 32        // output rows per wave tile
#define HALO 5
#define KSIZE 11
#define LROW 74      // 64 output cols + 2*5 halo staged per wave
#define NROWS (TH + 2*HALO)   // 42 input rows per tile

// 4 independent waves per block, each owning a private 64x32 output tile and a
// private LDS row buffer of float2{p,g}. No __syncthreads in the hot loop
// (cross-lane halo exchange is intra-wave; wave_barrier() fences ordering).
// float2 staging halves DS instruction count vs separate p/g arrays (b64 ops,
// mergeable to ds_read2_b64). Gaussian weights are compile-time constants
// (land in SGPRs, no expf preamble, no VGPR cost).
__global__ __launch_bounds__(256, 8)
void ssim_main(const float* __restrict__ pred, const float* __restrict__ gt,
               float* __restrict__ partial) {
    __shared__ float2 spg[4][LROW];
    __shared__ float wsum[4];

    const int tid  = threadIdx.x;
    const int wv   = tid >> 6;
    const int lane = tid & 63;
    const int bid  = blockIdx.x;
    const int img  = bid >> 5;            // 32 blocks per image
    const int rem  = bid & 31;
    const int c0   = (rem & 1) * 256 + wv * 64;  // 8 col tiles of 64
    const int r0   = (rem >> 1) * TH;            // 16 row chunks of 32

    // Gaussian 11-tap, sigma = 11/6, normalized (symmetric: W[k]=W[10-k]).
    constexpr float W[6] = {0.0052913f, 0.0201843f, 0.0571853f,
                            0.1203038f, 0.1879737f, 0.2181237f};

    const float* pimg = pred + (size_t)img * (IMG_H * IMG_W);
    const float* gimg = gt   + (size_t)img * (IMG_H * IMG_W);

    const int  cs0  = c0 - HALO + lane;      // staged col for this lane
    const int  cs1  = cs0 + 64;              // tail col (lanes 0..9)
    const bool has2 = lane < (LROW - 64);
    const bool c0ok = (cs0 >= 0) && (cs0 < IMG_W);
    const bool c1ok = has2 && (cs1 < IMG_W);
    const int  r_in0 = r0 - HALO;
    const int  rlast = r_in0 + NROWS - 1;

    float stp0, stp1, stg0, stg1;            // staged regs (next row)
    auto load_row = [&](int rr) {
        const bool rok = (rr >= 0) && (rr < IMG_H) && (rr <= rlast);
        const float* prow = pimg + (size_t)rr * IMG_W;
        const float* grow = gimg + (size_t)rr * IMG_W;
        stp0 = (rok && c0ok) ? prow[cs0] : 0.f;
        stg0 = (rok && c0ok) ? grow[cs0] : 0.f;
        stp1 = (rok && c1ok) ? prow[cs1] : 0.f;
        stg1 = (rok && c1ok) ? grow[cs1] : 0.f;
    };
    load_row(r_in0);

    // vertical ring: 5 fields x 11 rows, statically indexed
    float rp[KSIZE], rg[KSIZE], rpp[KSIZE], rgg[KSIZE], rpg[KSIZE];
    float lsum = 0.f;
    const float C1v = 1e-4f;   // 0.01^2
    const float C2v = 9e-4f;   // 0.03^2

    float2* sw = &spg[wv][0];

    auto step = [&](int i, auto jc) {
        constexpr int jj = decltype(jc)::value;   // ring slot = i mod 11
        const int r = r_in0 + i;

        __builtin_amdgcn_wave_barrier();   // prev row's reads before writes
        sw[lane] = make_float2(stp0, stg0);
        if (has2) sw[lane + 64] = make_float2(stp1, stg1);
        load_row(r + 1);                   // prefetch stays in flight
        __builtin_amdgcn_wave_barrier();   // writes before this row's reads

        // horizontal 11-tap conv, symmetric pairs, float2 reads (b64)
        float2 vc = sw[lane + 5];
        float t1 = W[5] * vc.x;
        float t2 = W[5] * vc.y;
        float hp = t1, hg = t2;
        float hpp = t1 * vc.x;
        float hgg = t2 * vc.y;
        float hpg = t1 * vc.y;
        #pragma unroll
        for (int k = 0; k < 5; ++k) {
            float2 vA = sw[lane + k];
            float2 vB = sw[lane + 10 - k];
            const float w = W[k];
            hp  = fmaf(w, vA.x + vB.x, hp);
            hg  = fmaf(w, vA.y + vB.y, hg);
            hpp = fmaf(w, fmaf(vA.x, vA.x, vB.x * vB.x), hpp);
            hgg = fmaf(w, fmaf(vA.y, vA.y, vB.y * vB.y), hgg);
            hpg = fmaf(w, fmaf(vA.x, vA.y, vB.x * vB.y), hpg);
        }
        rp[jj] = hp; rg[jj] = hg; rpp[jj] = hpp; rgg[jj] = hgg; rpg[jj] = hpg;

        // vertical 11-tap + SSIM once ring is full (output row = r-5)
        if (i >= 10 && i < NROWS) {
            float mu1 = 0.f, mu2 = 0.f, svpp = 0.f, svgg = 0.f, svpg = 0.f;
            #pragma unroll
            for (int d = 0; d < KSIZE; ++d) {
                const int slot = (jj + 1 + d) % KSIZE;   // constant-folded
                const float w = W[d < 6 ? d : 10 - d];
                mu1  = fmaf(w, rp[slot],  mu1);
                mu2  = fmaf(w, rg[slot],  mu2);
                svpp = fmaf(w, rpp[slot], svpp);
                svgg = fmaf(w, rgg[slot], svgg);
                svpg = fmaf(w, rpg[slot], svpg);
            }
            const float m11 = mu1 * mu1;
            const float m22 = mu2 * mu2;
            const float m12 = mu1 * mu2;
            const float s1  = svpp - m11;
            const float s2  = svgg - m22;
            const float s12 = svpg - m12;
            const float num = fmaf(2.f, m12, C1v) * fmaf(2.f, s12, C2v);
            const float den = (m11 + m22 + C1v) * (s1 + s2 + C2v);
            lsum += num * __builtin_amdgcn_rcpf(den);
        }
    };

    #define S_(I, J) step((I), std::integral_constant<int, (J)>{})
    #pragma unroll 1
    for (int ob = 0; ob < 3; ++ob) {
        const int b = ob * KSIZE;
        S_(b + 0, 0);  S_(b + 1, 1);  S_(b + 2, 2);  S_(b + 3, 3);
        S_(b + 4, 4);  S_(b + 5, 5);  S_(b + 6, 6);  S_(b + 7, 7);
        S_(b + 8, 8);  S_(b + 9, 9);  S_(b + 10, 10);
    }
    // epilogue: i = 33..41, ring slots 0..8 (33 % 11 == 0)
    S_(33, 0); S_(34, 1); S_(35, 2); S_(36, 3); S_(37, 4);
    S_(38, 5); S_(39, 6); S_(40, 7); S_(41, 8);
    #undef S_

    // per-wave shuffle reduction, one barrier outside the hot loop, one atomic
    #pragma unroll
    for (int off = 32; off > 0; off >>= 1) lsum += __shfl_down(lsum, off);
    if (lane == 0) wsum[wv] = lsum;
    __syncthreads();
    if (tid == 0) {
        float b = wsum[0] + wsum[1] + wsum[2] + wsum[3];
        atomicAdd(partial, b);
    }
}

__global__ void ssim_final(const float* __restrict__ partial,
                           float* __restrict__ out) {
    out[0] = 1.f - partial[0] * (1.f / (float)((size_t)NIMG * IMG_H * IMG_W));
}

extern "C" void kernel_launch(void* const* d_in, const int* in_sizes, int n_in,
                              void* d_out, int out_size, void* d_ws, size_t ws_size,
                              hipStream_t stream) {
    const float* pred = (const float*)d_in[0];
    const float* gt   = (const float*)d_in[1];
    float* out = (float*)d_out;
    float* ws  = (float*)d_ws;

    hipMemsetAsync(ws, 0, sizeof(float), stream);

    const int nblocks = NIMG * 32;   // 64 imgs * 8 col tiles * 16 row chunks / 4 waves
    ssim_main<<<nblocks, 256, 0, stream>>>(pred, gt, ws);
    ssim_final<<<1, 1, 0, stream>>>(ws, out);
}

// Round 6
// 264.726 us; speedup vs baseline: 2.2270x; 2.2270x over previous
//
#include <hip/hip_runtime.h>
#include <math.h>
#include <type_traits>

#define IMG_H 512
#define IMG_W 512
#define NIMG 64
#define TH 32        // output rows per wave tile
#define HALO 5
#define KSIZE 11
#define LROW 74      // 64 output cols + 2*5 halo staged per wave
#define NROWS (TH + 2*HALO)   // 42 input rows per tile

// 4 independent waves per block, each owning a private 64x32 output tile and a
// private LDS row buffer of float2{p,g}. No __syncthreads in the hot loop.
// launch_bounds(256,4): 128-VGPR budget — the 55-reg vertical ring MUST stay
// in registers (round 3's (256,8) forced a 64-VGPR cap -> spill -> 1.8 GB of
// scratch traffic -> 6x regression). Occupancy comes from the 2048-block grid
// (8 blocks/CU) + actual VGPR use (~64-72 -> 7-8 waves/SIMD), not the bound.
__global__ __launch_bounds__(256, 4)
void ssim_main(const float* __restrict__ pred, const float* __restrict__ gt,
               float* __restrict__ partial) {
    __shared__ float2 spg[4][LROW];
    __shared__ float wsum[4];

    const int tid  = threadIdx.x;
    const int wv   = tid >> 6;
    const int lane = tid & 63;
    const int bid  = blockIdx.x;
    const int img  = bid >> 5;            // 32 blocks per image
    const int rem  = bid & 31;
    const int c0   = (rem & 1) * 256 + wv * 64;  // 8 col tiles of 64
    const int r0   = (rem >> 1) * TH;            // 16 row chunks of 32

    // Gaussian 11-tap, sigma = 11/6, normalized (symmetric: W[k]=W[10-k]).
    constexpr float W[6] = {0.0052913f, 0.0201843f, 0.0571853f,
                            0.1203038f, 0.1879737f, 0.2181237f};

    const float* pimg = pred + (size_t)img * (IMG_H * IMG_W);
    const float* gimg = gt   + (size_t)img * (IMG_H * IMG_W);

    const int  cs0  = c0 - HALO + lane;      // staged col for this lane
    const int  cs1  = cs0 + 64;              // tail col (lanes 0..9)
    const bool has2 = lane < (LROW - 64);
    const bool c0ok = (cs0 >= 0) && (cs0 < IMG_W);
    const bool c1ok = has2 && (cs1 < IMG_W);
    const int  r_in0 = r0 - HALO;
    const int  rlast = r_in0 + NROWS - 1;

    float stp0, stp1, stg0, stg1;            // staged regs (next row)
    auto load_row = [&](int rr) {
        const bool rok = (rr >= 0) && (rr < IMG_H) && (rr <= rlast);
        const float* prow = pimg + (size_t)rr * IMG_W;
        const float* grow = gimg + (size_t)rr * IMG_W;
        stp0 = (rok && c0ok) ? prow[cs0] : 0.f;
        stg0 = (rok && c0ok) ? grow[cs0] : 0.f;
        stp1 = (rok && c1ok) ? prow[cs1] : 0.f;
        stg1 = (rok && c1ok) ? grow[cs1] : 0.f;
    };
    load_row(r_in0);

    // vertical ring: 5 fields x 11 rows, statically indexed
    float rp[KSIZE], rg[KSIZE], rpp[KSIZE], rgg[KSIZE], rpg[KSIZE];
    float lsum = 0.f;
    const float C1v = 1e-4f;   // 0.01^2
    const float C2v = 9e-4f;   // 0.03^2

    float2* sw = &spg[wv][0];

    auto step = [&](int i, auto jc) {
        constexpr int jj = decltype(jc)::value;   // ring slot = i mod 11
        const int r = r_in0 + i;

        __builtin_amdgcn_wave_barrier();   // prev row's reads before writes
        sw[lane] = make_float2(stp0, stg0);
        if (has2) sw[lane + 64] = make_float2(stp1, stg1);
        load_row(r + 1);                   // prefetch stays in flight
        __builtin_amdgcn_wave_barrier();   // writes before this row's reads

        // horizontal 11-tap conv, symmetric pairs, float2 reads (b64)
        float2 vc = sw[lane + 5];
        float t1 = W[5] * vc.x;
        float t2 = W[5] * vc.y;
        float hp = t1, hg = t2;
        float hpp = t1 * vc.x;
        float hgg = t2 * vc.y;
        float hpg = t1 * vc.y;
        #pragma unroll
        for (int k = 0; k < 5; ++k) {
            float2 vA = sw[lane + k];
            float2 vB = sw[lane + 10 - k];
            const float w = W[k];
            hp  = fmaf(w, vA.x + vB.x, hp);
            hg  = fmaf(w, vA.y + vB.y, hg);
            hpp = fmaf(w, fmaf(vA.x, vA.x, vB.x * vB.x), hpp);
            hgg = fmaf(w, fmaf(vA.y, vA.y, vB.y * vB.y), hgg);
            hpg = fmaf(w, fmaf(vA.x, vA.y, vB.x * vB.y), hpg);
        }
        rp[jj] = hp; rg[jj] = hg; rpp[jj] = hpp; rgg[jj] = hgg; rpg[jj] = hpg;

        // vertical 11-tap + SSIM once ring is full (output row = r-5)
        if (i >= 10 && i < NROWS) {
            float mu1 = 0.f, mu2 = 0.f, svpp = 0.f, svgg = 0.f, svpg = 0.f;
            #pragma unroll
            for (int d = 0; d < KSIZE; ++d) {
                const int slot = (jj + 1 + d) % KSIZE;   // constant-folded
                const float w = W[d < 6 ? d : 10 - d];
                mu1  = fmaf(w, rp[slot],  mu1);
                mu2  = fmaf(w, rg[slot],  mu2);
                svpp = fmaf(w, rpp[slot], svpp);
                svgg = fmaf(w, rgg[slot], svgg);
                svpg = fmaf(w, rpg[slot], svpg);
            }
            const float m11 = mu1 * mu1;
            const float m22 = mu2 * mu2;
            const float m12 = mu1 * mu2;
            const float s1  = svpp - m11;
            const float s2  = svgg - m22;
            const float s12 = svpg - m12;
            const float num = fmaf(2.f, m12, C1v) * fmaf(2.f, s12, C2v);
            const float den = (m11 + m22 + C1v) * (s1 + s2 + C2v);
            lsum += num * __builtin_amdgcn_rcpf(den);
        }
    };

    #define S_(I, J) step((I), std::integral_constant<int, (J)>{})
    #pragma unroll 1
    for (int ob = 0; ob < 3; ++ob) {
        const int b = ob * KSIZE;
        S_(b + 0, 0);  S_(b + 1, 1);  S_(b + 2, 2);  S_(b + 3, 3);
        S_(b + 4, 4);  S_(b + 5, 5);  S_(b + 6, 6);  S_(b + 7, 7);
        S_(b + 8, 8);  S_(b + 9, 9);  S_(b + 10, 10);
    }
    // epilogue: i = 33..41, ring slots 0..8 (33 % 11 == 0)
    S_(33, 0); S_(34, 1); S_(35, 2); S_(36, 3); S_(37, 4);
    S_(38, 5); S_(39, 6); S_(40, 7); S_(41, 8);
    #undef S_

    // per-wave shuffle reduction, one barrier outside the hot loop, one atomic
    #pragma unroll
    for (int off = 32; off > 0; off >>= 1) lsum += __shfl_down(lsum, off);
    if (lane == 0) wsum[wv] = lsum;
    __syncthreads();
    if (tid == 0) {
        float b = wsum[0] + wsum[1] + wsum[2] + wsum[3];
        atomicAdd(partial, b);
    }
}

__global__ void ssim_final(const float* __restrict__ partial,
                           float* __restrict__ out) {
    out[0] = 1.f - partial[0] * (1.f / (float)((size_t)NIMG * IMG_H * IMG_W));
}

extern "C" void kernel_launch(void* const* d_in, const int* in_sizes, int n_in,
                              void* d_out, int out_size, void* d_ws, size_t ws_size,
                              hipStream_t stream) {
    const float* pred = (const float*)d_in[0];
    const float* gt   = (const float*)d_in[1];
    float* out = (float*)d_out;
    float* ws  = (float*)d_ws;

    hipMemsetAsync(ws, 0, sizeof(float), stream);

    const int nblocks = NIMG * 32;   // 64 imgs * 8 col tiles * 16 row chunks / 4 waves
    ssim_main<<<nblocks, 256, 0, stream>>>(pred, gt, ws);
    ssim_final<<<1, 1, 0, stream>>>(ws, out);
}

// Round 7
// 189.143 us; speedup vs baseline: 3.1169x; 1.3996x over previous
//
#include <hip/hip_runtime.h>
#include <math.h>
#include <type_traits>

#define IMG_H 512
#define IMG_W 512
#define NIMG 64
#define TH 32        // output rows per wave tile
#define HALO 5
#define KSIZE 11
#define LROW 74      // 64 output cols + 2*5 halo staged per wave
#define NROWS (TH + 2*HALO)   // 42 input rows per tile

// Round-2 structure verbatim (known no-spill: VGPR 60, WRITE_SIZE 32 KB),
// with ONLY the geometry changed: TH 64->32, grid 1024->2048 blocks, so
// occupancy is no longer grid-capped (8 blocks/CU, up to 32 waves/CU).
// 4 independent waves per block, each owning a private 64x32 output tile and
// a private LDS row buffer. No __syncthreads in the hot loop; intra-wave
// halo exchange fenced by wave_barrier(). Uniform 44-step loop (4 x 11 ring
// slots); 2 padded steps load clamped zeros and skip compute.
__global__ __launch_bounds__(256, 4)
void ssim_main(const float* __restrict__ pred, const float* __restrict__ gt,
               float* __restrict__ partial) {
    __shared__ float sp[4][LROW];
    __shared__ float sg[4][LROW];
    __shared__ float wsum[4];

    const int tid  = threadIdx.x;
    const int wv   = tid >> 6;
    const int lane = tid & 63;
    const int bid  = blockIdx.x;
    const int img  = bid >> 5;            // 32 blocks per image
    const int rem  = bid & 31;
    const int c0   = (rem & 1) * 256 + wv * 64;  // wave's first output col
    const int r0   = (rem >> 1) * TH;            // wave's first output row

    // Gaussian window (sigma = 11/6, normalized) — matches reference.
    float wgt[KSIZE];
    {
        const float sigma = 11.0f / 6.0f;
        float s = 0.f;
        #pragma unroll
        for (int i = 0; i < KSIZE; ++i) {
            float d = (float)(i - 5);
            wgt[i] = expf(-d * d / (2.f * sigma * sigma));
            s += wgt[i];
        }
        float inv = 1.f / s;
        #pragma unroll
        for (int i = 0; i < KSIZE; ++i) wgt[i] *= inv;
    }

    const float* pimg = pred + (size_t)img * IMG_H * IMG_W;
    const float* gimg = gt   + (size_t)img * IMG_H * IMG_W;

    const int  cs0  = c0 - HALO + lane;      // staged col for this lane
    const int  cs1  = cs0 + 64;              // tail col (lanes 0..9)
    const bool has2 = lane < (LROW - 64);
    const bool c0ok = (cs0 >= 0) && (cs0 < IMG_W);
    const bool c1ok = has2 && (cs1 < IMG_W);
    const int  r_in0 = r0 - HALO;
    const int  rlast = r_in0 + NROWS - 1;    // last input row actually needed

    float stp0, stp1, stg0, stg1;            // staged regs (next row)
    auto load_row = [&](int rr) {
        const bool rok = (rr >= 0) && (rr < IMG_H) && (rr <= rlast);
        const float* prow = pimg + (size_t)rr * IMG_W;
        const float* grow = gimg + (size_t)rr * IMG_W;
        stp0 = (rok && c0ok) ? prow[cs0] : 0.f;
        stg0 = (rok && c0ok) ? grow[cs0] : 0.f;
        stp1 = (rok && c1ok) ? prow[cs1] : 0.f;
        stg1 = (rok && c1ok) ? grow[cs1] : 0.f;
    };
    load_row(r_in0);

    // vertical ring: 5 arrays x 11 rows, statically indexed (constexpr jj)
    float rp[KSIZE], rg[KSIZE], rpp[KSIZE], rgg[KSIZE], rpg[KSIZE];
    float lsum = 0.f;
    const float C1v = 1e-4f;   // 0.01^2
    const float C2v = 9e-4f;   // 0.03^2

    float* swp = &sp[wv][0];
    float* swg = &sg[wv][0];

    auto step = [&](int i, auto jc) {
        constexpr int jj = decltype(jc)::value;   // ring slot, static
        const int r = r_in0 + i;

        // fence: previous row's LDS reads stay before this row's writes
        __builtin_amdgcn_wave_barrier();

        // 1) commit staged regs (row r) to this wave's LDS row
        swp[lane] = stp0;
        swg[lane] = stg0;
        if (has2) { swp[lane + 64] = stp1; swg[lane + 64] = stg1; }

        // 2) issue loads for row r+1 (stay in flight through this row's compute)
        load_row(r + 1);

        // fence: this row's writes stay before this row's reads
        __builtin_amdgcn_wave_barrier();

        // 3) horizontal 11-tap conv at column c0+lane
        float hp = 0.f, hg = 0.f, hpp = 0.f, hgg = 0.f, hpg = 0.f;
        #pragma unroll
        for (int k = 0; k < KSIZE; ++k) {
            float p  = swp[lane + k];
            float g  = swg[lane + k];
            float t1 = wgt[k] * p;
            float t2 = wgt[k] * g;
            hp += t1;
            hg += t2;
            hpp = fmaf(t1, p, hpp);
            hgg = fmaf(t2, g, hgg);
            hpg = fmaf(t1, g, hpg);
        }
        rp[jj] = hp; rg[jj] = hg; rpp[jj] = hpp; rgg[jj] = hgg; rpg[jj] = hpg;

        // 4) vertical conv + SSIM once ring is full (output row = r-5)
        if (i >= 10 && i < NROWS) {
            float mu1 = 0.f, mu2 = 0.f, svpp = 0.f, svgg = 0.f, svpg = 0.f;
            #pragma unroll
            for (int d = 0; d < KSIZE; ++d) {
                const int slot = (jj + 1 + d) % KSIZE;  // constant-folded
                const float wv2 = wgt[d];
                mu1  = fmaf(wv2, rp[slot],  mu1);
                mu2  = fmaf(wv2, rg[slot],  mu2);
                svpp = fmaf(wv2, rpp[slot], svpp);
                svgg = fmaf(wv2, rgg[slot], svgg);
                svpg = fmaf(wv2, rpg[slot], svpg);
            }
            const float m11 = mu1 * mu1;
            const float m22 = mu2 * mu2;
            const float m12 = mu1 * mu2;
            const float s1  = svpp - m11;
            const float s2  = svgg - m22;
            const float s12 = svpg - m12;
            const float num = fmaf(2.f, m12, C1v) * fmaf(2.f, s12, C2v);
            const float den = (m11 + m22 + C1v) * (s1 + s2 + C2v);
            lsum += num * __builtin_amdgcn_rcpf(den);
        }
    };

    #pragma unroll 1
    for (int ob = 0; ob < 4; ++ob) {
        const int base = ob * KSIZE;
        step(base + 0,  std::integral_constant<int, 0>{});
        step(base + 1,  std::integral_constant<int, 1>{});
        step(base + 2,  std::integral_constant<int, 2>{});
        step(base + 3,  std::integral_constant<int, 3>{});
        step(base + 4,  std::integral_constant<int, 4>{});
        step(base + 5,  std::integral_constant<int, 5>{});
        step(base + 6,  std::integral_constant<int, 6>{});
        step(base + 7,  std::integral_constant<int, 7>{});
        step(base + 8,  std::integral_constant<int, 8>{});
        step(base + 9,  std::integral_constant<int, 9>{});
        step(base + 10, std::integral_constant<int, 10>{});
    }

    // per-wave shuffle reduction, one barrier outside hot loop, one atomic
    #pragma unroll
    for (int off = 32; off > 0; off >>= 1) lsum += __shfl_down(lsum, off);
    if (lane == 0) wsum[wv] = lsum;
    __syncthreads();
    if (tid == 0) {
        float b = wsum[0] + wsum[1] + wsum[2] + wsum[3];
        atomicAdd(partial, b);
    }
}

__global__ void ssim_final(const float* __restrict__ partial,
                           float* __restrict__ out) {
    out[0] = 1.f - partial[0] * (1.f / (float)((size_t)NIMG * IMG_H * IMG_W));
}

extern "C" void kernel_launch(void* const* d_in, const int* in_sizes, int n_in,
                              void* d_out, int out_size, void* d_ws, size_t ws_size,
                              hipStream_t stream) {
    const float* pred = (const float*)d_in[0];
    const float* gt   = (const float*)d_in[1];
    float* out = (float*)d_out;
    float* ws  = (float*)d_ws;

    hipMemsetAsync(ws, 0, sizeof(float), stream);

    const int nblocks = NIMG * 32;   // 64 imgs * 2 col strips * 16 row chunks
    ssim_main<<<nblocks, 256, 0, stream>>>(pred, gt, ws);
    ssim_final<<<1, 1, 0, stream>>>(ws, out);
}